// Round 16
// baseline (733.492 us; speedup 1.0000x reference)
//
#include <hip/hip_runtime.h>
#include <hip/hip_bf16.h>
#include <cstdint>

#define T_TOKENS 2048
#define HIDDEN 2048
#define INTER 1408
#define NEXP 16
#define TOPK 4
#define SINTER 2816
#define CAP 768
#define BK 32

typedef __attribute__((ext_vector_type(8))) short short8;
typedef __attribute__((ext_vector_type(8))) unsigned short ushort8;
typedef __attribute__((ext_vector_type(4))) float f32x4;

__device__ __forceinline__ float4 ld4f(const float* p) {
  return *reinterpret_cast<const float4*>(p);
}

__device__ __forceinline__ unsigned short f2bf(float v) {
  unsigned int u = __float_as_uint(v);
  unsigned int r = (u + 0x7FFFu + ((u >> 16) & 1u)) >> 16;  // RNE
  return (unsigned short)r;
}

__device__ __forceinline__ void gld16(const void* g, void* l) {
  __builtin_amdgcn_global_load_lds(
      (const __attribute__((address_space(1))) void*)g,
      (__attribute__((address_space(3))) void*)l, 16, 0, 0);
}

// ---------------- router: logits -> softmax -> top4 (+ fused x->bf16 convert) --------
__global__ __launch_bounds__(64) void router_kernel(
    const float* __restrict__ x, const float* __restrict__ wg,
    int* __restrict__ topi, float* __restrict__ topw,
    unsigned short* __restrict__ xb)
{
  const int t = blockIdx.x;
  const int lane = threadIdx.x;
  float acc[NEXP];
#pragma unroll
  for (int e = 0; e < NEXP; ++e) acc[e] = 0.f;
  const float* xr = x + (size_t)t * HIDDEN;
  unsigned short* xbr = xb + (size_t)t * HIDDEN;
  for (int i = lane; i < HIDDEN; i += 64) {
    float xv = xr[i];
    xbr[i] = f2bf(xv);
#pragma unroll
    for (int e = 0; e < NEXP; ++e) acc[e] += xv * wg[e * HIDDEN + i];
  }
#pragma unroll
  for (int e = 0; e < NEXP; ++e) {
#pragma unroll
    for (int off = 32; off > 0; off >>= 1)
      acc[e] += __shfl_xor(acc[e], off);
  }
  float m = acc[0];
#pragma unroll
  for (int e = 1; e < NEXP; ++e) m = fmaxf(m, acc[e]);
  float p[NEXP];
  float s = 0.f;
#pragma unroll
  for (int e = 0; e < NEXP; ++e) { p[e] = expf(acc[e] - m); s += p[e]; }
  const float inv = 1.f / s;
#pragma unroll
  for (int e = 0; e < NEXP; ++e) p[e] *= inv;
  if (lane == 0) {
#pragma unroll
    for (int k = 0; k < TOPK; ++k) {
      float best = -1.f; int bi = 0;
#pragma unroll
      for (int e = 0; e < NEXP; ++e)
        if (p[e] > best) { best = p[e]; bi = e; }   // strict >: lowest idx on tie
      topi[t * TOPK + k] = bi;
      topw[t * TOPK + k] = best;  // ROUTED_SCALE = 1.0
      p[bi] = -1.f;
    }
  }
}

// ------------- stable partition: slot -> (expert,pos), exact cumsum order -------------
__global__ __launch_bounds__(1024) void partition_kernel(
    const int* __restrict__ topi, float* __restrict__ topw,
    int* __restrict__ rowtok, int* __restrict__ count)
{
  __shared__ int se[T_TOKENS * TOPK];
  for (int i = threadIdx.x; i < T_TOKENS * TOPK; i += 1024) se[i] = topi[i];
  __syncthreads();

  const int wave = threadIdx.x >> 6;
  const int lane = threadIdx.x & 63;
  const uint64_t below = (lane == 0) ? 0ull : ((~0ull) >> (64 - lane));
  int base = 0;
  for (int c = 0; c < T_TOKENS * TOPK; c += 64) {
    int ev = se[c + lane];
    uint64_t mask = __ballot(ev == wave);
    if (ev == wave) {
      int my = base + __popcll(mask & below);
      if (my < CAP) rowtok[wave * CAP + my] = c + lane;
      else          topw[c + lane] = 0.f;
    }
    base += __popcll(mask);
  }
  if (lane == 0) count[wave] = base < CAP ? base : CAP;
}

// ------------- transpose + convert (merged two-weight form) ------
__global__ __launch_bounds__(256) void tcvt_w_kernel(
    const float* __restrict__ W0, const float* __restrict__ W1,
    unsigned short* __restrict__ T,
    int K, int N, long tz, int mul, int nz0, int which0, int which1)
{
  const int z = blockIdx.z;
  const float* W; int which; long zz;
  if (z < nz0) { W = W0; which = which0; zz = z; }
  else         { W = W1; which = which1; zz = z - nz0; }
  W += zz * (long)K * N;
  T += zz * tz;
  const int k0 = blockIdx.x * 64, n0 = blockIdx.y * 64;
  __shared__ float tile[64][65];
  const int tr = threadIdx.x >> 4;
  const int tc4 = (threadIdx.x & 15) * 4;
#pragma unroll
  for (int p = 0; p < 4; ++p) {
    int r = p * 16 + tr;
    float4 v = ld4f(W + (long)(k0 + r) * N + n0 + tc4);
    tile[r][tc4] = v.x; tile[r][tc4 + 1] = v.y;
    tile[r][tc4 + 2] = v.z; tile[r][tc4 + 3] = v.w;
  }
  __syncthreads();
  const int wn = threadIdx.x >> 3;          // 0..31
  const int wk = (threadIdx.x & 7) * 8;     // 0..56
#pragma unroll
  for (int p = 0; p < 2; ++p) {
    int n = p * 32 + wn;
    unsigned short o[8];
#pragma unroll
    for (int j = 0; j < 8; ++j) o[j] = f2bf(tile[wk + j][n]);
    const int gn = n0 + n;
    const long prow = ((long)(gn >> 4) * mul + which) * 16 + (gn & 15);
    *(ushort8*)(T + prow * K + k0 + wk) = *(ushort8*)&o[0];
  }
}

// ================= 256x256 8-phase kernel (m201 schedule, interleaved halves) =======
// BK=64/tile, 2 tiles/iter (d0: phases1-4, d1: phases5-8), 512 thr = 8 waves (2Mx4N),
// per-wave 128x64 out (acc 8x4). LDS 128KB: sA/sB[2 dbuf][2 half][128x64].
// Interleaved halves: A-half h = 64-row blocks {h,h+2} (quadrant mh reads half mh);
// B-half h = 32-col blocks {h,h+2,h+4,h+6} (quadrant nh reads half nh).
// Phase: 12 ds_read_b128 -> stage slot -> barrier -> lgkm(0)+schedbar -> setprio(1)
// 16 MFMA setprio(0) -> [vmcnt(4) @p4,p8; vmcnt(0) last iter p4] -> barrier.
// Stage ledger (write-safe + read-confirmed, audited):
//  p1:{Bh1,Ah1}(d1,T+1)  p3:Ah0(d0,T+2)  p4:Bh0(d0,T+2)  p5:{Bh1,Ah1}(d0,T+2)
//  p7:Ah0(d1,T+3)  p8:Bh0(d1,T+3).  vmcnt(4)=2 newest halves in flight.
// EPI=2: fused SwiGLU (interleaved B) -> bf16 H. EPI=3: atomic combine into out.
#define PHASE8(D, MH, NH, STAGES, VMS)                                          \
  {                                                                             \
    short8 fa[4][2], fb[2][2];                                                  \
    _Pragma("unroll")                                                           \
    for (int mi = 0; mi < 4; ++mi)                                              \
      _Pragma("unroll")                                                         \
      for (int kk = 0; kk < 2; ++kk) {                                          \
        const int idx = wm * 64 + mi * 16 + fr;                                 \
        const int pc = (kk * 4 + fc) ^ (fr & 7);                                \
        fa[mi][kk] = *(const short8*)&sA[D][MH][idx * 64 + pc * 8];             \
      }                                                                         \
    _Pragma("unroll")                                                           \
    for (int ni = 0; ni < 2; ++ni)                                              \
      _Pragma("unroll")                                                         \
      for (int kk = 0; kk < 2; ++kk) {                                          \
        const int idx = wn * 32 + ni * 16 + fr;                                 \
        const int pc = (kk * 4 + fc) ^ (fr & 7);                                \
        fb[ni][kk] = *(const short8*)&sB[D][NH][idx * 64 + pc * 8];             \
      }                                                                         \
    STAGES;                                                                     \
    __builtin_amdgcn_s_barrier();                                               \
    asm volatile("s_waitcnt lgkmcnt(0)" ::: "memory");                          \
    __builtin_amdgcn_sched_barrier(0);                                          \
    __builtin_amdgcn_s_setprio(1);                                              \
    _Pragma("unroll")                                                           \
    for (int mi = 0; mi < 4; ++mi)                                              \
      _Pragma("unroll")                                                         \
      for (int ni = 0; ni < 2; ++ni)                                            \
        _Pragma("unroll")                                                       \
        for (int kk = 0; kk < 2; ++kk)                                          \
          acc[MH * 4 + mi][NH * 2 + ni] =                                       \
              __builtin_amdgcn_mfma_f32_16x16x32_bf16(                          \
                  fa[mi][kk], fb[ni][kk], acc[MH * 4 + mi][NH * 2 + ni], 0, 0, 0); \
    __builtin_amdgcn_s_setprio(0);                                              \
    VMS;                                                                        \
    __builtin_amdgcn_s_barrier();                                               \
  }

template<int EPI>
__global__ __launch_bounds__(512, 1)
void gemm_bf8(const unsigned short* __restrict__ Ag, int ldka,
              const unsigned short* __restrict__ Bg, long bstride,
              float* __restrict__ C, unsigned short* __restrict__ H, int ldc,
              const float* __restrict__ TW,
              const int* __restrict__ arows_g, int ashift, long aexp,
              const int* __restrict__ crows_g, long cexp,
              const int* __restrict__ cnt, int Mfix, int K,
              int MT, int NTn)
{
  const int nwg = gridDim.x;
  const int lin = (blockIdx.x & 7) * (nwg >> 3) + (blockIdx.x >> 3);
  const int mt = lin % MT;
  const int rest = lin / MT;
  const int nt = rest % NTn;
  const int e = rest / NTn;

  const int M = cnt ? cnt[e] : Mfix;
  if (mt * 256 >= M) return;
  const int n0 = nt * 256;

  const int tid = threadIdx.x;
  const int l = tid & 63;
  const int w = tid >> 6;       // 0..7
  const int wm = w >> 2;        // 0..1 -> rows wm*128
  const int wn = w & 3;         // 0..3 -> cols wn*64
  const int fr = l & 15;
  const int fc = l >> 4;

  const int* arows = arows_g ? arows_g + e * CAP : nullptr;
  const int* crows = crows_g ? crows_g + e * CAP : nullptr;
  const unsigned short* Bexp = Bg + (long)e * bstride;

  __shared__ __align__(16) unsigned short sA[2][2][128 * 64];   // 64 KB
  __shared__ __align__(16) unsigned short sB[2][2][128 * 64];   // 64 KB

  // staging: half-row index i = j*64 + w*8 + (l>>3); chunk l&7; swizzled source chunk
  const int sc = ((l & 7) ^ ((l >> 3) & 7)) * 8;
  long aoffh[2][2], boffh[2][2];
#pragma unroll
  for (int h = 0; h < 2; ++h)
#pragma unroll
    for (int j = 0; j < 2; ++j) {
      const int i = j * 64 + w * 8 + (l >> 3);
      // A: interleaved row r = (i>>6)*128 + h*64 + (i&63)
      {
        const int rt = ((i >> 6) << 7) + h * 64 + (i & 63);
        int r = mt * 256 + rt;
        if (r > M - 1) r = M - 1;
        const long arow = arows ? (long)(arows[r] >> ashift) : (aexp * e + r);
        aoffh[h][j] = arow * (long)ldka + sc;
      }
      // B: interleaved col n = (i>>5)*64 + h*32 + (i&31)
      {
        const int ntc = ((i >> 5) << 6) + h * 32 + (i & 31);
        boffh[h][j] = (long)(n0 + ntc) * K + sc;
      }
    }

  f32x4 acc[8][4];
#pragma unroll
  for (int i = 0; i < 8; ++i)
#pragma unroll
    for (int j = 0; j < 4; ++j) acc[i][j] = (f32x4)0.f;

  const int NT2 = K / 64;        // even (32 or 22)
  const int NITER = NT2 / 2;

  auto stgA = [&](int d, int h, int t) {
#pragma unroll
    for (int j = 0; j < 2; ++j)
      gld16(Ag + aoffh[h][j] + (long)t * 64, &sA[d][h][(j * 64 + w * 8) * 64]);
  };
  auto stgB = [&](int d, int h, int t) {
#pragma unroll
    for (int j = 0; j < 2; ++j)
      gld16(Bexp + boffh[h][j] + (long)t * 64, &sB[d][h][(j * 64 + w * 8) * 64]);
  };

  // prologue: tile0 full -> d0; Ah0,Bh0(tile1) -> d1; confirm tile0.
  stgA(0, 0, 0); stgB(0, 0, 0); stgA(0, 1, 0); stgB(0, 1, 0);
  stgA(1, 0, 1); stgB(1, 0, 1);
  asm volatile("s_waitcnt vmcnt(4)" ::: "memory");
  __builtin_amdgcn_s_barrier();

  for (int it = 0; it < NITER; ++it) {
    const int t0 = 2 * it;
    const bool nl = (it + 1 < NITER);
    PHASE8(0, 0, 0, { stgB(1, 1, t0 + 1); stgA(1, 1, t0 + 1); }, (void)0);
    PHASE8(0, 0, 1, (void)0, (void)0);
    PHASE8(0, 1, 0, { if (t0 + 2 < NT2) stgA(0, 0, t0 + 2); }, (void)0);
    PHASE8(0, 1, 1, { if (t0 + 2 < NT2) stgB(0, 0, t0 + 2); },
           { if (nl) asm volatile("s_waitcnt vmcnt(4)" ::: "memory");
             else    asm volatile("s_waitcnt vmcnt(0)" ::: "memory"); });
    PHASE8(1, 0, 0, { if (t0 + 2 < NT2) { stgB(0, 1, t0 + 2); stgA(0, 1, t0 + 2); } }, (void)0);
    PHASE8(1, 0, 1, (void)0, (void)0);
    PHASE8(1, 1, 0, { if (t0 + 3 < NT2) stgA(1, 0, t0 + 3); }, (void)0);
    PHASE8(1, 1, 1, { if (t0 + 3 < NT2) stgB(1, 0, t0 + 3); },
           { if (nl) asm volatile("s_waitcnt vmcnt(4)" ::: "memory");
             else    asm volatile("s_waitcnt vmcnt(0)" ::: "memory"); });
  }

  // epilogue: acc[a][nj]; row = wm*128 + (a>>2)*64 + (a&3)*16 + fc*4 + rr;
  // col = wn*64 + nj*16 + fr (== (nj>>1)*32 + (nj&1)*16 + ...).
#pragma unroll
  for (int a = 0; a < 8; ++a)
#pragma unroll
    for (int rr = 0; rr < 4; ++rr) {
      const int r = mt * 256 + wm * 128 + (a >> 2) * 64 + (a & 3) * 16 + fc * 4 + rr;
      if (r >= M) continue;
      if constexpr (EPI == 2) {
        const long crow = crows ? (long)crows[r] : (cexp * e + r);
#pragma unroll
        for (int nh = 0; nh < 2; ++nh) {
          const float g = acc[a][nh * 2 + 0][rr];
          const float u = acc[a][nh * 2 + 1][rr];
          const float hv = u * (g / (1.f + __expf(-g)));   // silu(g)*u
          const int col = (n0 / 32 + wn * 2 + nh) * 16 + fr;  // logical col
          H[crow * (long)ldc + col] = f2bf(hv);
        }
      } else if constexpr (EPI == 3) {
        const int slot = crows[r];
        const float wgt = TW[slot];
        if (wgt != 0.f) {
          const long tok = slot >> 2;
#pragma unroll
          for (int nj = 0; nj < 4; ++nj) {
            const int col = n0 + wn * 64 + nj * 16 + fr;
            atomicAdd(&C[tok * (long)ldc + col], wgt * acc[a][nj][rr]);
          }
        }
      } else {
        const long crow = crows ? (long)crows[r] : (cexp * e + r);
#pragma unroll
        for (int nj = 0; nj < 4; ++nj) {
          const int col = n0 + wn * 64 + nj * 16 + fr;
          C[crow * (long)ldc + col] = acc[a][nj][rr];
        }
      }
    }
}

// ------------- 128x128 depth-2 kernel (proven R8/R14) — shared down -------------
template<int EPI>
__global__ __launch_bounds__(256, 2)
void gemm_bf(const unsigned short* __restrict__ Ag, int ldka,
             const unsigned short* __restrict__ Bg, long bstride,
             float* __restrict__ C, unsigned short* __restrict__ H, int ldc,
             const int* __restrict__ arows_g, int ashift, long aexp,
             const int* __restrict__ crows_g, long cexp,
             const int* __restrict__ cnt, int Mfix, int K,
             int MT, int NTn)
{
  const int nwg = gridDim.x;
  const int lin = (blockIdx.x & 7) * (nwg >> 3) + (blockIdx.x >> 3);
  const int mt = lin % MT;
  const int rest = lin / MT;
  const int nt = rest % NTn;
  const int e = rest / NTn;

  const int M = cnt ? cnt[e] : Mfix;
  if (mt * 128 >= M) return;
  const int n0 = nt * 128;

  const int tid = threadIdx.x;
  const int l = tid & 63;
  const int w = tid >> 6;
  const int wm = w >> 1;
  const int wn = w & 1;
  const int fr = l & 15;
  const int fc = l >> 4;

  const int* arows = arows_g ? arows_g + e * CAP : nullptr;
  const int* crows = crows_g ? crows_g + e * CAP : nullptr;
  const unsigned short* Bexp = Bg + (long)e * bstride;

  __shared__ __align__(16) unsigned short sA[3][128 * BK];
  __shared__ __align__(16) unsigned short sB[3][128 * BK];

  const int rb_s = ((l >> 3) & 1) | (((l >> 5) & 1) << 1);
  const int sch = ((l & 3) ^ rb_s) * 8;
  long aoff[2], boff[2];
#pragma unroll
  for (int j = 0; j < 2; ++j) {
    const int rloc = j * 64 + w * 16 + (l >> 2);
    int r = mt * 128 + rloc;
    if (r > M - 1) r = M - 1;
    const long arow = arows ? (long)(arows[r] >> ashift) : (aexp * e + r);
    aoff[j] = arow * (long)ldka + sch;
    boff[j] = (long)(n0 + rloc) * K + sch;
  }

  const int rb_r = ((fr >> 1) & 1) | (((fr >> 3) & 1) << 1);
  const int pcoff = (fc ^ rb_r) * 8;

  f32x4 acc[4][4];
#pragma unroll
  for (int i = 0; i < 4; ++i)
#pragma unroll
    for (int j = 0; j < 4; ++j) acc[i][j] = (f32x4)0.f;

  const int NT = K / BK;

  auto stage = [&](int buf, int kt) {
#pragma unroll
    for (int j = 0; j < 2; ++j) {
      gld16(Ag + aoff[j] + kt, &sA[buf][(j * 64 + w * 16) * BK]);
      gld16(Bexp + boff[j] + kt, &sB[buf][(j * 64 + w * 16) * BK]);
    }
  };

  stage(0, 0);
  stage(1, BK);

  int rb = 0, wb = 2;
  for (int t = 0; t < NT; ++t) {
    if (t + 1 < NT) asm volatile("s_waitcnt vmcnt(4)" ::: "memory");
    else            asm volatile("s_waitcnt vmcnt(0)" ::: "memory");
    __builtin_amdgcn_s_barrier();
    __builtin_amdgcn_sched_barrier(0);

    if (t + 2 < NT) stage(wb, (t + 2) * BK);

    short8 fa[4], fb[4];
#pragma unroll
    for (int mi = 0; mi < 4; ++mi)
      fa[mi] = *(const short8*)&sA[rb][(wm * 64 + mi * 16 + fr) * BK + pcoff];
#pragma unroll
    for (int ni = 0; ni < 4; ++ni)
      fb[ni] = *(const short8*)&sB[rb][(wn * 64 + ni * 16 + fr) * BK + pcoff];
#pragma unroll
    for (int mi = 0; mi < 4; ++mi)
#pragma unroll
      for (int ni = 0; ni < 4; ++ni)
        acc[mi][ni] = __builtin_amdgcn_mfma_f32_16x16x32_bf16(fa[mi], fb[ni], acc[mi][ni], 0, 0, 0);

    rb = (rb == 2) ? 0 : rb + 1;
    wb = (wb == 2) ? 0 : wb + 1;
  }

#pragma unroll
  for (int mi = 0; mi < 4; ++mi)
#pragma unroll
    for (int rr = 0; rr < 4; ++rr) {
      const int r = mt * 128 + wm * 64 + mi * 16 + fc * 4 + rr;
      if (r >= M) continue;
      const long crow = crows ? (long)crows[r] : (cexp * e + r);
#pragma unroll
      for (int ni = 0; ni < 4; ++ni) {
        const int col = n0 + wn * 64 + ni * 16 + fr;
        C[crow * (long)ldc + col] = acc[mi][ni][rr];
      }
    }
}

extern "C" void kernel_launch(void* const* d_in, const int* in_sizes, int n_in,
                              void* d_out, int out_size, void* d_ws, size_t ws_size,
                              hipStream_t stream)
{
  const float* x   = (const float*)d_in[0];
  const float* wg  = (const float*)d_in[1];
  const float* w1  = (const float*)d_in[2];
  const float* w3  = (const float*)d_in[3];
  const float* w2  = (const float*)d_in[4];
  const float* ws1 = (const float*)d_in[5];
  const float* ws3 = (const float*)d_in[6];
  const float* ws2 = (const float*)d_in[7];
  float* out = (float*)d_out;

  char* w = (char*)d_ws;
  int*   topi   = (int*)w;   w += (size_t)T_TOKENS * TOPK * 4;
  float* topw   = (float*)w; w += (size_t)T_TOKENS * TOPK * 4;
  int*   rowtok = (int*)w;   w += (size_t)NEXP * CAP * 4;
  int*   count  = (int*)w;   w += 256;
  uintptr_t a = (uintptr_t)w; a = (a + 255) & ~(uintptr_t)255; w = (char*)a;

  const size_t XSZ  = (size_t)T_TOKENS * HIDDEN;
  const size_t WSI  = (size_t)2 * HIDDEN * SINTER;
  const size_t WRI  = (size_t)2 * NEXP * HIDDEN * INTER;
  const size_t HSSZ = (size_t)T_TOKENS * SINTER;
  const size_t HRSZ = (size_t)NEXP * CAP * INTER;

  unsigned short* xb  = (unsigned short*)w; w += XSZ * 2;
  unsigned short* wSi = (unsigned short*)w; w += WSI * 2;
  unsigned short* wRi = (unsigned short*)w; w += WRI * 2;
  unsigned short* hs  = (unsigned short*)w; w += HSSZ * 2;
  unsigned short* hr  = (unsigned short*)w; w += HRSZ * 2;
  unsigned short* wS2 = wSi;
  unsigned short* wR2 = wRi;

  router_kernel<<<T_TOKENS, 64, 0, stream>>>(x, wg, topi, topw, xb);
  partition_kernel<<<1, 1024, 0, stream>>>(topi, topw, rowtok, count);

  // ---- shared upgate: hs = silu(x@ws1) * (x@ws3) — 256^2 8-phase, grid 176 ----
  tcvt_w_kernel<<<dim3(HIDDEN / 64, SINTER / 64, 2), 256, 0, stream>>>(
      ws1, ws3, wSi, HIDDEN, SINTER, 0L, 2, 1, 0, 1);
  gemm_bf8<2><<<(T_TOKENS / 256) * (2 * SINTER / 256), 512, 0, stream>>>(
      xb, HIDDEN, wSi, 0L, nullptr, hs, SINTER, nullptr,
      nullptr, 0, 0L, nullptr, 0L,
      nullptr, T_TOKENS, HIDDEN, T_TOKENS / 256, 2 * SINTER / 256);

  // ---- routed upgate: hr = silu(gx@w1[e]) * (gx@w3[e]) — 256^2 8-phase, grid 528 ----
  tcvt_w_kernel<<<dim3(HIDDEN / 64, INTER / 64, 2 * NEXP), 256, 0, stream>>>(
      w1, w3, wRi, HIDDEN, INTER, (long)2 * HIDDEN * INTER, 2, NEXP, 0, 1);
  gemm_bf8<2><<<(CAP / 256) * (2 * INTER / 256) * NEXP, 512, 0, stream>>>(
      xb, HIDDEN, wRi, (long)2 * HIDDEN * INTER, nullptr, hr, INTER, nullptr,
      rowtok, 2, 0L, nullptr, (long)CAP,
      count, 0, HIDDEN, CAP / 256, 2 * INTER / 256);

  // ---- shared down: out = hs @ ws2 — proven 128^2 kernel, grid 256 ----
  tcvt_w_kernel<<<dim3(SINTER / 64, HIDDEN / 64, 1), 256, 0, stream>>>(
      ws2, ws2, wS2, SINTER, HIDDEN, 0L, 1, 1, 0, 0);
  gemm_bf<0><<<(T_TOKENS / 128) * (HIDDEN / 128), 256, 0, stream>>>(
      hs, SINTER, wS2, 0L, out, nullptr, HIDDEN,
      nullptr, 0, 0L, nullptr, 0L,
      nullptr, T_TOKENS, SINTER, T_TOKENS / 128, HIDDEN / 128);

  // ---- routed down, fused combine: out[token] += topw[slot]*(hr@w2[e]) — grid 384 ----
  tcvt_w_kernel<<<dim3(INTER / 64, HIDDEN / 64, NEXP), 256, 0, stream>>>(
      w2, w2, wR2, INTER, HIDDEN, (long)INTER * HIDDEN, 1, NEXP, 0, 0);
  gemm_bf8<3><<<(CAP / 256) * (HIDDEN / 256) * NEXP, 512, 0, stream>>>(
      hr, INTER, wR2, (long)INTER * HIDDEN, out, nullptr, HIDDEN, topw,
      nullptr, 0, (long)CAP, rowtok, 0L,
      count, 0, INTER, CAP / 256, HIDDEN / 256);
}

// Round 17
// 627.686 us; speedup vs baseline: 1.1686x; 1.1686x over previous
//
#include <hip/hip_runtime.h>
#include <hip/hip_bf16.h>
#include <cstdint>

#define T_TOKENS 2048
#define HIDDEN 2048
#define INTER 1408
#define NEXP 16
#define TOPK 4
#define SINTER 2816
#define CAP 768
#define BK 32

typedef __attribute__((ext_vector_type(8))) short short8;
typedef __attribute__((ext_vector_type(8))) unsigned short ushort8;
typedef __attribute__((ext_vector_type(4))) float f32x4;

__device__ __forceinline__ float4 ld4f(const float* p) {
  return *reinterpret_cast<const float4*>(p);
}

__device__ __forceinline__ unsigned short f2bf(float v) {
  unsigned int u = __float_as_uint(v);
  unsigned int r = (u + 0x7FFFu + ((u >> 16) & 1u)) >> 16;  // RNE
  return (unsigned short)r;
}

__device__ __forceinline__ void gld16(const void* g, void* l) {
  __builtin_amdgcn_global_load_lds(
      (const __attribute__((address_space(1))) void*)g,
      (__attribute__((address_space(3))) void*)l, 16, 0, 0);
}

// ---------------- router: logits -> softmax -> top4 ----------------
__global__ __launch_bounds__(64) void router_kernel(
    const float* __restrict__ x, const float* __restrict__ wg,
    int* __restrict__ topi, float* __restrict__ topw)
{
  const int t = blockIdx.x;
  const int lane = threadIdx.x;
  float acc[NEXP];
#pragma unroll
  for (int e = 0; e < NEXP; ++e) acc[e] = 0.f;
  const float* xr = x + (size_t)t * HIDDEN;
  for (int i = lane; i < HIDDEN; i += 64) {
    float xv = xr[i];
#pragma unroll
    for (int e = 0; e < NEXP; ++e) acc[e] += xv * wg[e * HIDDEN + i];
  }
#pragma unroll
  for (int e = 0; e < NEXP; ++e) {
#pragma unroll
    for (int off = 32; off > 0; off >>= 1)
      acc[e] += __shfl_xor(acc[e], off);
  }
  float m = acc[0];
#pragma unroll
  for (int e = 1; e < NEXP; ++e) m = fmaxf(m, acc[e]);
  float p[NEXP];
  float s = 0.f;
#pragma unroll
  for (int e = 0; e < NEXP; ++e) { p[e] = expf(acc[e] - m); s += p[e]; }
  const float inv = 1.f / s;
#pragma unroll
  for (int e = 0; e < NEXP; ++e) p[e] *= inv;
  if (lane == 0) {
#pragma unroll
    for (int k = 0; k < TOPK; ++k) {
      float best = -1.f; int bi = 0;
#pragma unroll
      for (int e = 0; e < NEXP; ++e)
        if (p[e] > best) { best = p[e]; bi = e; }   // strict >: lowest idx on tie
      topi[t * TOPK + k] = bi;
      topw[t * TOPK + k] = best;  // ROUTED_SCALE = 1.0
      p[bi] = -1.f;
    }
  }
}

// ------------- stable partition: slot -> (expert,pos), exact cumsum order -------------
__global__ __launch_bounds__(1024) void partition_kernel(
    const int* __restrict__ topi, float* __restrict__ topw,
    int* __restrict__ rowtok, int* __restrict__ count)
{
  __shared__ int se[T_TOKENS * TOPK];
  for (int i = threadIdx.x; i < T_TOKENS * TOPK; i += 1024) se[i] = topi[i];
  __syncthreads();

  const int wave = threadIdx.x >> 6;
  const int lane = threadIdx.x & 63;
  const uint64_t below = (lane == 0) ? 0ull : ((~0ull) >> (64 - lane));
  int base = 0;
  for (int c = 0; c < T_TOKENS * TOPK; c += 64) {
    int ev = se[c + lane];
    uint64_t mask = __ballot(ev == wave);
    if (ev == wave) {
      int my = base + __popcll(mask & below);
      if (my < CAP) rowtok[wave * CAP + my] = c + lane;
      else          topw[c + lane] = 0.f;
    }
    base += __popcll(mask);
  }
  if (lane == 0) count[wave] = base < CAP ? base : CAP;
}

// ------------- convert x -> bf16 -------------
__global__ __launch_bounds__(256) void cvt_x_kernel(
    const float* __restrict__ x, unsigned short* __restrict__ xb)
{
  const long i = ((long)blockIdx.x * 256 + threadIdx.x) * 8;
  float4 a = ld4f(x + i), b = ld4f(x + i + 4);
  float v[8] = {a.x, a.y, a.z, a.w, b.x, b.y, b.z, b.w};
  unsigned short o[8];
#pragma unroll
  for (int j = 0; j < 8; ++j) o[j] = f2bf(v[j]);
  *(ushort8*)(xb + i) = *(ushort8*)&o[0];
}

// ------------- transpose + convert (merged two-weight form) ------
// z < nz0: weight W0/which0, expert z; z >= nz0: W1/which1, expert z-nz0.
// prow(n) = ((n>>4)*mul + which)*16 + (n&15).
__global__ __launch_bounds__(256) void tcvt_w_kernel(
    const float* __restrict__ W0, const float* __restrict__ W1,
    unsigned short* __restrict__ T,
    int K, int N, long tz, int mul, int nz0, int which0, int which1)
{
  const int z = blockIdx.z;
  const float* W; int which; long zz;
  if (z < nz0) { W = W0; which = which0; zz = z; }
  else         { W = W1; which = which1; zz = z - nz0; }
  W += zz * (long)K * N;
  T += zz * tz;
  const int k0 = blockIdx.x * 64, n0 = blockIdx.y * 64;
  __shared__ float tile[64][65];
  const int tr = threadIdx.x >> 4;
  const int tc4 = (threadIdx.x & 15) * 4;
#pragma unroll
  for (int p = 0; p < 4; ++p) {
    int r = p * 16 + tr;
    float4 v = ld4f(W + (long)(k0 + r) * N + n0 + tc4);
    tile[r][tc4] = v.x; tile[r][tc4 + 1] = v.y;
    tile[r][tc4 + 2] = v.z; tile[r][tc4 + 3] = v.w;
  }
  __syncthreads();
  const int wn = threadIdx.x >> 3;          // 0..31
  const int wk = (threadIdx.x & 7) * 8;     // 0..56
#pragma unroll
  for (int p = 0; p < 2; ++p) {
    int n = p * 32 + wn;
    unsigned short o[8];
#pragma unroll
    for (int j = 0; j < 8; ++j) o[j] = f2bf(tile[wk + j][n]);
    const int gn = n0 + n;
    const long prow = ((long)(gn >> 4) * mul + which) * 16 + (gn & 15);
    *(ushort8*)(T + prow * K + k0 + wk) = *(ushort8*)&o[0];
  }
}

// ------------- bf16 MFMA GEMM, depth-2 counted prefetch, swizzled LDS -------------
// Template NW = waves (4: 128x128 tile — the PROVEN R8/R14 config; 8: 128x256 tile).
// Per-wave geometry: 64x64 out, acc 4x4, 8 ds_read_b128 + 16 MFMA per K-step.
// 3-buffer LDS. Pipeline (R8-proven): prologue stages tiles 0,1; iter t:
// vmcnt(loads/iter) [stage(t) done, issued 2 iters ago] -> barrier ->
// stage(t+2) -> ds_read -> MFMA. XOR chunk swizzle: 0 bank conflicts.
// EPI=0: C fp32. EPI=2: fused SwiGLU on 16-col-interleaved B -> bf16 H.
// EPI=3: fused combine: atomicAdd(out[token], topw[slot]*acc) (routed down).
template<int NW, int EPI>
__global__ __launch_bounds__(NW * 64, 2)
void gemm_bf(const unsigned short* __restrict__ Ag, int ldka,
             const unsigned short* __restrict__ Bg, long bstride,
             float* __restrict__ C, unsigned short* __restrict__ H, int ldc,
             const float* __restrict__ TW,
             const int* __restrict__ arows_g, int ashift, long aexp,
             const int* __restrict__ crows_g, long cexp,
             const int* __restrict__ cnt, int Mfix, int K,
             int MT, int NTn)
{
  constexpr int TN = NW * 32;        // tile N: 128 or 256
  constexpr int GA = 8 / NW;         // A 16-row groups per wave: 2 or 1
  constexpr int WN = NW / 2;         // waves along N: 2 or 4

  const int nwg = gridDim.x;
  const int lin = (blockIdx.x & 7) * (nwg >> 3) + (blockIdx.x >> 3);
  const int mt = lin % MT;
  const int rest = lin / MT;
  const int nt = rest % NTn;
  const int e = rest / NTn;

  const int M = cnt ? cnt[e] : Mfix;
  if (mt * 128 >= M) return;
  const int n0 = nt * TN;

  const int tid = threadIdx.x;
  const int l = tid & 63;
  const int w = tid >> 6;
  const int wm = w / WN;             // 0..1
  const int wn = w % WN;             // 0..WN-1
  const int fr = l & 15;
  const int fc = l >> 4;

  const int* arows = arows_g ? arows_g + e * CAP : nullptr;
  const int* crows = crows_g ? crows_g + e * CAP : nullptr;
  const unsigned short* Bexp = Bg + (long)e * bstride;

  __shared__ __align__(16) unsigned short sA[3][128 * BK];
  __shared__ __align__(16) unsigned short sB[3][TN * BK];

  // staging: 16-row group g: lane l -> row g*16 + (l>>2), chunk l&3.
  // pre-swizzle source chunk by dest-row bits {1,3} (= bits of l>>2):
  const int rb_s = ((l >> 3) & 1) | (((l >> 5) & 1) << 1);
  const int sch = ((l & 3) ^ rb_s) * 8;
  long aoff[GA], boff[2];
#pragma unroll
  for (int j = 0; j < GA; ++j) {
    const int rloc = (w * GA + j) * 16 + (l >> 2);   // 0..127
    int r = mt * 128 + rloc;
    if (r > M - 1) r = M - 1;
    const long arow = arows ? (long)(arows[r] >> ashift) : (aexp * e + r);
    aoff[j] = arow * (long)ldka + sch;
  }
#pragma unroll
  for (int j = 0; j < 2; ++j) {
    const int rloc = (w * 2 + j) * 16 + (l >> 2);    // 0..TN-1
    boff[j] = (long)(n0 + rloc) * K + sch;
  }

  // fragment-read swizzle: physical chunk = fc ^ bits{1,3}(fr)
  const int rb_r = ((fr >> 1) & 1) | (((fr >> 3) & 1) << 1);
  const int pcoff = (fc ^ rb_r) * 8;

  f32x4 acc[4][4];
#pragma unroll
  for (int i = 0; i < 4; ++i)
#pragma unroll
    for (int j = 0; j < 4; ++j) acc[i][j] = (f32x4)0.f;

  const int NT = K / BK;

  auto stage = [&](int buf, int kt) {
#pragma unroll
    for (int j = 0; j < GA; ++j)
      gld16(Ag + aoff[j] + kt, &sA[buf][(w * GA + j) * 16 * BK]);
#pragma unroll
    for (int j = 0; j < 2; ++j)
      gld16(Bexp + boff[j] + kt, &sB[buf][(w * 2 + j) * 16 * BK]);
  };

  stage(0, 0);
  stage(1, BK);

  int rb = 0, wb = 2;
  for (int t = 0; t < NT; ++t) {
    // stage(t) (GA+2 loads) was issued two iterations ago: force it complete,
    // allow the newest stage (t+1) to stay in flight.
    if (t + 1 < NT) {
      if constexpr (NW == 8) asm volatile("s_waitcnt vmcnt(3)" ::: "memory");
      else                   asm volatile("s_waitcnt vmcnt(4)" ::: "memory");
    } else {
      asm volatile("s_waitcnt vmcnt(0)" ::: "memory");
    }
    __builtin_amdgcn_s_barrier();          // all waves' stage(t) landed; all prior
    __builtin_amdgcn_sched_barrier(0);     // reads of buf[wb] retired (pin order)

    if (t + 2 < NT) stage(wb, (t + 2) * BK);

    short8 fa[4], fb[4];
#pragma unroll
    for (int mi = 0; mi < 4; ++mi)
      fa[mi] = *(const short8*)&sA[rb][(wm * 64 + mi * 16 + fr) * BK + pcoff];
#pragma unroll
    for (int ni = 0; ni < 4; ++ni)
      fb[ni] = *(const short8*)&sB[rb][(wn * 64 + ni * 16 + fr) * BK + pcoff];
#pragma unroll
    for (int mi = 0; mi < 4; ++mi)
#pragma unroll
      for (int ni = 0; ni < 4; ++ni)
        acc[mi][ni] = __builtin_amdgcn_mfma_f32_16x16x32_bf16(fa[mi], fb[ni], acc[mi][ni], 0, 0, 0);

    rb = (rb == 2) ? 0 : rb + 1;
    wb = (wb == 2) ? 0 : wb + 1;
  }

  // epilogue: C/D layout col=lane&15, row=(lane>>4)*4+rr
#pragma unroll
  for (int mi = 0; mi < 4; ++mi)
#pragma unroll
    for (int rr = 0; rr < 4; ++rr) {
      const int r = mt * 128 + wm * 64 + mi * 16 + fc * 4 + rr;
      if (r >= M) continue;
      if constexpr (EPI == 2) {
        const long crow = crows ? (long)crows[r] : (cexp * e + r);
#pragma unroll
        for (int np = 0; np < 2; ++np) {
          const float g = acc[mi][2 * np][rr];
          const float u = acc[mi][2 * np + 1][rr];
          const float h = u * (g / (1.f + __expf(-g)));   // silu(g)*u
          const int i = (n0 / 32 + wn * 2 + np) * 16 + fr;  // logical col
          H[crow * (long)ldc + i] = f2bf(h);
        }
      } else if constexpr (EPI == 3) {
        const int slot = crows[r];
        const float wgt = TW[slot];
        if (wgt != 0.f) {
          const long tok = slot >> 2;
#pragma unroll
          for (int ni = 0; ni < 4; ++ni) {
            const int col = n0 + wn * 64 + ni * 16 + fr;
            atomicAdd(&C[tok * (long)ldc + col], wgt * acc[mi][ni][rr]);
          }
        }
      } else {
        const long crow = crows ? (long)crows[r] : (cexp * e + r);
#pragma unroll
        for (int ni = 0; ni < 4; ++ni) {
          const int col = n0 + wn * 64 + ni * 16 + fr;
          C[crow * (long)ldc + col] = acc[mi][ni][rr];
        }
      }
    }
}

extern "C" void kernel_launch(void* const* d_in, const int* in_sizes, int n_in,
                              void* d_out, int out_size, void* d_ws, size_t ws_size,
                              hipStream_t stream)
{
  const float* x   = (const float*)d_in[0];
  const float* wg  = (const float*)d_in[1];
  const float* w1  = (const float*)d_in[2];
  const float* w3  = (const float*)d_in[3];
  const float* w2  = (const float*)d_in[4];
  const float* ws1 = (const float*)d_in[5];
  const float* ws3 = (const float*)d_in[6];
  const float* ws2 = (const float*)d_in[7];
  float* out = (float*)d_out;

  char* w = (char*)d_ws;
  int*   topi   = (int*)w;   w += (size_t)T_TOKENS * TOPK * 4;
  float* topw   = (float*)w; w += (size_t)T_TOKENS * TOPK * 4;
  int*   rowtok = (int*)w;   w += (size_t)NEXP * CAP * 4;
  int*   count  = (int*)w;   w += 256;
  uintptr_t a = (uintptr_t)w; a = (a + 255) & ~(uintptr_t)255; w = (char*)a;

  const size_t XSZ  = (size_t)T_TOKENS * HIDDEN;            // 4.19M
  const size_t WSI  = (size_t)2 * HIDDEN * SINTER;          // 11.5M  (interleaved ws1/ws3)
  const size_t WRI  = (size_t)2 * NEXP * HIDDEN * INTER;    // 92.3M  (interleaved w1/w3)
  const size_t HSSZ = (size_t)T_TOKENS * SINTER;            // 5.77M
  const size_t HRSZ = (size_t)NEXP * CAP * INTER;           // 17.3M

  unsigned short* xb  = (unsigned short*)w; w += XSZ * 2;   // 8.4 MB
  unsigned short* wSi = (unsigned short*)w; w += WSI * 2;   // 23.1 MB; reused as ws2T
  unsigned short* wRi = (unsigned short*)w; w += WRI * 2;   // 184.5 MB; reused as w2T
  unsigned short* hs  = (unsigned short*)w; w += HSSZ * 2;  // 11.5 MB
  unsigned short* hr  = (unsigned short*)w; w += HRSZ * 2;  // 34.6 MB
  unsigned short* wS2 = wSi;                                // after shared upgate GEMM
  unsigned short* wR2 = wRi;                                // after routed upgate GEMM

  router_kernel<<<T_TOKENS, 64, 0, stream>>>(x, wg, topi, topw);
  partition_kernel<<<1, 1024, 0, stream>>>(topi, topw, rowtok, count);
  cvt_x_kernel<<<(int)(XSZ / (256 * 8)), 256, 0, stream>>>(x, xb);

  // ---- shared upgate: hs = silu(x@ws1) * (x@ws3), fused via interleaved weights ----
  tcvt_w_kernel<<<dim3(HIDDEN / 64, SINTER / 64, 2), 256, 0, stream>>>(
      ws1, ws3, wSi, HIDDEN, SINTER, 0L, 2, 1, 0, 1);
  gemm_bf<4, 2><<<(T_TOKENS / 128) * (2 * SINTER / 128), 256, 0, stream>>>(
      xb, HIDDEN, wSi, 0L, nullptr, hs, SINTER, nullptr,
      nullptr, 0, 0L, nullptr, 0L,
      nullptr, T_TOKENS, HIDDEN, T_TOKENS / 128, 2 * SINTER / 128);

  // ---- routed upgate: hr = silu(gather(x)@w1[e]) * (gather(x)@w3[e]) ----
  tcvt_w_kernel<<<dim3(HIDDEN / 64, INTER / 64, 2 * NEXP), 256, 0, stream>>>(
      w1, w3, wRi, HIDDEN, INTER, (long)2 * HIDDEN * INTER, 2, NEXP, 0, 1);
  gemm_bf<4, 2><<<(CAP / 128) * (2 * INTER / 128) * NEXP, 256, 0, stream>>>(
      xb, HIDDEN, wRi, (long)2 * HIDDEN * INTER, nullptr, hr, INTER, nullptr,
      rowtok, 2, 0L, nullptr, (long)CAP,
      count, 0, HIDDEN, CAP / 128, 2 * INTER / 128);

  // ---- shared down: out = hs @ ws2 (proven 128^2 4-wave kernel, grid 256) ----
  tcvt_w_kernel<<<dim3(SINTER / 64, HIDDEN / 64, 1), 256, 0, stream>>>(
      ws2, ws2, wS2, SINTER, HIDDEN, 0L, 1, 1, 0, 0);
  gemm_bf<4, 0><<<(T_TOKENS / 128) * (HIDDEN / 128), 256, 0, stream>>>(
      hs, SINTER, wS2, 0L, out, nullptr, HIDDEN, nullptr,
      nullptr, 0, 0L, nullptr, 0L,
      nullptr, T_TOKENS, SINTER, T_TOKENS / 128, HIDDEN / 128);

  // ---- routed down, fused combine: out[token] += topw[slot] * (hr @ w2[e]) ----
  tcvt_w_kernel<<<dim3(INTER / 64, HIDDEN / 64, NEXP), 256, 0, stream>>>(
      w2, w2, wR2, INTER, HIDDEN, (long)INTER * HIDDEN, 1, NEXP, 0, 0);
  gemm_bf<4, 3><<<(CAP / 128) * (HIDDEN / 128) * NEXP, 256, 0, stream>>>(
      hr, INTER, wR2, (long)INTER * HIDDEN, out, nullptr, HIDDEN, topw,
      nullptr, 0, (long)CAP, rowtok, 0L,
      count, 0, INTER, CAP / 128, HIDDEN / 128);
}

// Round 18
// 583.771 us; speedup vs baseline: 1.2565x; 1.0752x over previous
//
#include <hip/hip_runtime.h>
#include <hip/hip_bf16.h>
#include <cstdint>

#define T_TOKENS 2048
#define HIDDEN 2048
#define INTER 1408
#define NEXP 16
#define TOPK 4
#define SINTER 2816
#define CAP 768
#define BK 32

typedef __attribute__((ext_vector_type(8))) short short8;
typedef __attribute__((ext_vector_type(8))) unsigned short ushort8;
typedef __attribute__((ext_vector_type(4))) float f32x4;

__device__ __forceinline__ float4 ld4f(const float* p) {
  return *reinterpret_cast<const float4*>(p);
}

__device__ __forceinline__ unsigned short f2bf(float v) {
  unsigned int u = __float_as_uint(v);
  unsigned int r = (u + 0x7FFFu + ((u >> 16) & 1u)) >> 16;  // RNE
  return (unsigned short)r;
}

__device__ __forceinline__ void gld16(const void* g, void* l) {
  __builtin_amdgcn_global_load_lds(
      (const __attribute__((address_space(1))) void*)g,
      (__attribute__((address_space(3))) void*)l, 16, 0, 0);
}

// ---------------- router: logits -> softmax -> top4 ----------------
__global__ __launch_bounds__(64) void router_kernel(
    const float* __restrict__ x, const float* __restrict__ wg,
    int* __restrict__ topi, float* __restrict__ topw)
{
  const int t = blockIdx.x;
  const int lane = threadIdx.x;
  float acc[NEXP];
#pragma unroll
  for (int e = 0; e < NEXP; ++e) acc[e] = 0.f;
  const float* xr = x + (size_t)t * HIDDEN;
  for (int i = lane; i < HIDDEN; i += 64) {
    float xv = xr[i];
#pragma unroll
    for (int e = 0; e < NEXP; ++e) acc[e] += xv * wg[e * HIDDEN + i];
  }
#pragma unroll
  for (int e = 0; e < NEXP; ++e) {
#pragma unroll
    for (int off = 32; off > 0; off >>= 1)
      acc[e] += __shfl_xor(acc[e], off);
  }
  float m = acc[0];
#pragma unroll
  for (int e = 1; e < NEXP; ++e) m = fmaxf(m, acc[e]);
  float p[NEXP];
  float s = 0.f;
#pragma unroll
  for (int e = 0; e < NEXP; ++e) { p[e] = expf(acc[e] - m); s += p[e]; }
  const float inv = 1.f / s;
#pragma unroll
  for (int e = 0; e < NEXP; ++e) p[e] *= inv;
  if (lane == 0) {
#pragma unroll
    for (int k = 0; k < TOPK; ++k) {
      float best = -1.f; int bi = 0;
#pragma unroll
      for (int e = 0; e < NEXP; ++e)
        if (p[e] > best) { best = p[e]; bi = e; }   // strict >: lowest idx on tie
      topi[t * TOPK + k] = bi;
      topw[t * TOPK + k] = best;  // ROUTED_SCALE = 1.0
      p[bi] = -1.f;
    }
  }
}

// ------------- stable partition: slot -> (expert,pos), exact cumsum order -------------
__global__ __launch_bounds__(1024) void partition_kernel(
    const int* __restrict__ topi, float* __restrict__ topw,
    int* __restrict__ rowtok, int* __restrict__ count)
{
  __shared__ int se[T_TOKENS * TOPK];
  for (int i = threadIdx.x; i < T_TOKENS * TOPK; i += 1024) se[i] = topi[i];
  __syncthreads();

  const int wave = threadIdx.x >> 6;
  const int lane = threadIdx.x & 63;
  const uint64_t below = (lane == 0) ? 0ull : ((~0ull) >> (64 - lane));
  int base = 0;
  for (int c = 0; c < T_TOKENS * TOPK; c += 64) {
    int ev = se[c + lane];
    uint64_t mask = __ballot(ev == wave);
    if (ev == wave) {
      int my = base + __popcll(mask & below);
      if (my < CAP) rowtok[wave * CAP + my] = c + lane;
      else          topw[c + lane] = 0.f;
    }
    base += __popcll(mask);
  }
  if (lane == 0) count[wave] = base < CAP ? base : CAP;
}

// ------------- convert x -> bf16 -------------
__global__ __launch_bounds__(256) void cvt_x_kernel(
    const float* __restrict__ x, unsigned short* __restrict__ xb)
{
  const long i = ((long)blockIdx.x * 256 + threadIdx.x) * 8;
  float4 a = ld4f(x + i), b = ld4f(x + i + 4);
  float v[8] = {a.x, a.y, a.z, a.w, b.x, b.y, b.z, b.w};
  unsigned short o[8];
#pragma unroll
  for (int j = 0; j < 8; ++j) o[j] = f2bf(v[j]);
  *(ushort8*)(xb + i) = *(ushort8*)&o[0];
}

// ------------- tcvt body (device): transpose + convert one 64x64 tile ------
// prow(n) = ((n>>4)*mul + which)*16 + (n&15).
__device__ __forceinline__ void tcvt_body(
    int bx, int by, int bz,
    const float* W0, const float* W1, unsigned short* T,
    int K, int N, long tz, int mul, int nz0, int which0, int which1,
    float (*tile)[65])
{
  const float* W; int which; long zz;
  if (bz < nz0) { W = W0; which = which0; zz = bz; }
  else          { W = W1; which = which1; zz = bz - nz0; }
  W += zz * (long)K * N;
  T += zz * tz;
  const int k0 = bx * 64, n0 = by * 64;
  const int tr = threadIdx.x >> 4;
  const int tc4 = (threadIdx.x & 15) * 4;
#pragma unroll
  for (int p = 0; p < 4; ++p) {
    int r = p * 16 + tr;
    float4 v = ld4f(W + (long)(k0 + r) * N + n0 + tc4);
    tile[r][tc4] = v.x; tile[r][tc4 + 1] = v.y;
    tile[r][tc4 + 2] = v.z; tile[r][tc4 + 3] = v.w;
  }
  __syncthreads();
  const int wn = threadIdx.x >> 3;          // 0..31
  const int wk = (threadIdx.x & 7) * 8;     // 0..56
#pragma unroll
  for (int p = 0; p < 2; ++p) {
    int n = p * 32 + wn;
    unsigned short o[8];
#pragma unroll
    for (int j = 0; j < 8; ++j) o[j] = f2bf(tile[wk + j][n]);
    const int gn = n0 + n;
    const long prow = ((long)(gn >> 4) * mul + which) * 16 + (gn & 15);
    *(ushort8*)(T + prow * K + k0 + wk) = *(ushort8*)&o[0];
  }
}

// ------------- standalone tcvt (merged two-weight form) ------
__global__ __launch_bounds__(256) void tcvt_w_kernel(
    const float* __restrict__ W0, const float* __restrict__ W1,
    unsigned short* __restrict__ T,
    int K, int N, long tz, int mul, int nz0, int which0, int which1)
{
  __shared__ float tile[64][65];
  tcvt_body(blockIdx.x, blockIdx.y, blockIdx.z, W0, W1, T, K, N, tz, mul,
            nz0, which0, which1, tile);
}

// ------------- bf16 MFMA GEMM, depth-2 counted prefetch, swizzled LDS -------------
// NW=4: 128x128 tile — PROVEN R8/R14 config. Per-wave: 64x64 out, acc 4x4,
// 8 ds_read_b128 + 16 MFMA per K-step. 3-buffer LDS (48 KB).
// Pipeline (R8-proven): prologue stages tiles 0,1; iter t: vmcnt [stage(t) done,
// issued 2 iters ago] -> barrier -> stage(t+2) -> ds_read -> MFMA. XOR chunk
// swizzle: 0 bank conflicts.
// EPI=0: C fp32. EPI=2: fused SwiGLU on 16-col-interleaved B -> bf16 H.
// EPI=3: fused combine: atomicAdd(out[token], topw[slot]*acc) (routed down).
// R18: INDEPENDENT-WORK TAIL — blocks >= gemmBlocks run tcvt_body for the NEXT
// stage's weights (no data dependency; stream order still fences consumers).
// Tail reuses sA as the 64x65 fp32 tile (16.6 KB < 24 KB).
template<int NW, int EPI>
__global__ __launch_bounds__(NW * 64, 2)
void gemm_bf(const unsigned short* __restrict__ Ag, int ldka,
             const unsigned short* __restrict__ Bg, long bstride,
             float* __restrict__ C, unsigned short* __restrict__ H, int ldc,
             const float* __restrict__ TW,
             const int* __restrict__ arows_g, int ashift, long aexp,
             const int* __restrict__ crows_g, long cexp,
             const int* __restrict__ cnt, int Mfix, int K,
             int MT, int NTn,
             const float* tW0, const float* tW1, unsigned short* tT,
             int tK, int tN, long ttz, int tmul, int tnz0, int tw0, int tw1,
             int tKX, int tNY, int gemmBlocks)
{
  constexpr int TN = NW * 32;        // tile N: 128 or 256
  constexpr int GA = 8 / NW;         // A 16-row groups per wave: 2 or 1
  constexpr int WN = NW / 2;         // waves along N: 2 or 4

  __shared__ __align__(16) unsigned short sA[3][128 * BK];
  __shared__ __align__(16) unsigned short sB[3][TN * BK];

  if ((int)blockIdx.x >= gemmBlocks) {
    // ---- tcvt tail block ----
    const int tbid = (int)blockIdx.x - gemmBlocks;
    const int bx = tbid % tKX;
    const int rest2 = tbid / tKX;
    const int by = rest2 % tNY;
    const int bz = rest2 / tNY;
    tcvt_body(bx, by, bz, tW0, tW1, tT, tK, tN, ttz, tmul, tnz0, tw0, tw1,
              (float(*)[65])&sA[0][0]);
    return;
  }

  const int lin = (blockIdx.x & 7) * (gemmBlocks >> 3) + (blockIdx.x >> 3);
  const int mt = lin % MT;
  const int rest = lin / MT;
  const int nt = rest % NTn;
  const int e = rest / NTn;

  const int M = cnt ? cnt[e] : Mfix;
  if (mt * 128 >= M) return;
  const int n0 = nt * TN;

  const int tid = threadIdx.x;
  const int l = tid & 63;
  const int w = tid >> 6;
  const int wm = w / WN;             // 0..1
  const int wn = w % WN;             // 0..WN-1
  const int fr = l & 15;
  const int fc = l >> 4;

  const int* arows = arows_g ? arows_g + e * CAP : nullptr;
  const int* crows = crows_g ? crows_g + e * CAP : nullptr;
  const unsigned short* Bexp = Bg + (long)e * bstride;

  // staging: 16-row group g: lane l -> row g*16 + (l>>2), chunk l&3.
  // pre-swizzle source chunk by dest-row bits {1,3} (= bits of l>>2):
  const int rb_s = ((l >> 3) & 1) | (((l >> 5) & 1) << 1);
  const int sch = ((l & 3) ^ rb_s) * 8;
  long aoff[GA], boff[2];
#pragma unroll
  for (int j = 0; j < GA; ++j) {
    const int rloc = (w * GA + j) * 16 + (l >> 2);   // 0..127
    int r = mt * 128 + rloc;
    if (r > M - 1) r = M - 1;
    const long arow = arows ? (long)(arows[r] >> ashift) : (aexp * e + r);
    aoff[j] = arow * (long)ldka + sch;
  }
#pragma unroll
  for (int j = 0; j < 2; ++j) {
    const int rloc = (w * 2 + j) * 16 + (l >> 2);    // 0..TN-1
    boff[j] = (long)(n0 + rloc) * K + sch;
  }

  // fragment-read swizzle: physical chunk = fc ^ bits{1,3}(fr)
  const int rb_r = ((fr >> 1) & 1) | (((fr >> 3) & 1) << 1);
  const int pcoff = (fc ^ rb_r) * 8;

  f32x4 acc[4][4];
#pragma unroll
  for (int i = 0; i < 4; ++i)
#pragma unroll
    for (int j = 0; j < 4; ++j) acc[i][j] = (f32x4)0.f;

  const int NT = K / BK;

  auto stage = [&](int buf, int kt) {
#pragma unroll
    for (int j = 0; j < GA; ++j)
      gld16(Ag + aoff[j] + kt, &sA[buf][(w * GA + j) * 16 * BK]);
#pragma unroll
    for (int j = 0; j < 2; ++j)
      gld16(Bexp + boff[j] + kt, &sB[buf][(w * 2 + j) * 16 * BK]);
  };

  stage(0, 0);
  stage(1, BK);

  int rb = 0, wb = 2;
  for (int t = 0; t < NT; ++t) {
    // stage(t) (GA+2 loads) was issued two iterations ago: force it complete,
    // allow the newest stage (t+1) to stay in flight.
    if (t + 1 < NT) {
      if constexpr (NW == 8) asm volatile("s_waitcnt vmcnt(3)" ::: "memory");
      else                   asm volatile("s_waitcnt vmcnt(4)" ::: "memory");
    } else {
      asm volatile("s_waitcnt vmcnt(0)" ::: "memory");
    }
    __builtin_amdgcn_s_barrier();          // all waves' stage(t) landed; all prior
    __builtin_amdgcn_sched_barrier(0);     // reads of buf[wb] retired (pin order)

    if (t + 2 < NT) stage(wb, (t + 2) * BK);

    short8 fa[4], fb[4];
#pragma unroll
    for (int mi = 0; mi < 4; ++mi)
      fa[mi] = *(const short8*)&sA[rb][(wm * 64 + mi * 16 + fr) * BK + pcoff];
#pragma unroll
    for (int ni = 0; ni < 4; ++ni)
      fb[ni] = *(const short8*)&sB[rb][(wn * 64 + ni * 16 + fr) * BK + pcoff];
#pragma unroll
    for (int mi = 0; mi < 4; ++mi)
#pragma unroll
      for (int ni = 0; ni < 4; ++ni)
        acc[mi][ni] = __builtin_amdgcn_mfma_f32_16x16x32_bf16(fa[mi], fb[ni], acc[mi][ni], 0, 0, 0);

    rb = (rb == 2) ? 0 : rb + 1;
    wb = (wb == 2) ? 0 : wb + 1;
  }

  // epilogue: C/D layout col=lane&15, row=(lane>>4)*4+rr
#pragma unroll
  for (int mi = 0; mi < 4; ++mi)
#pragma unroll
    for (int rr = 0; rr < 4; ++rr) {
      const int r = mt * 128 + wm * 64 + mi * 16 + fc * 4 + rr;
      if (r >= M) continue;
      if constexpr (EPI == 2) {
        const long crow = crows ? (long)crows[r] : (cexp * e + r);
#pragma unroll
        for (int np = 0; np < 2; ++np) {
          const float g = acc[mi][2 * np][rr];
          const float u = acc[mi][2 * np + 1][rr];
          const float h = u * (g / (1.f + __expf(-g)));   // silu(g)*u
          const int i = (n0 / 32 + wn * 2 + np) * 16 + fr;  // logical col
          H[crow * (long)ldc + i] = f2bf(h);
        }
      } else if constexpr (EPI == 3) {
        const int slot = crows[r];
        const float wgt = TW[slot];
        if (wgt != 0.f) {
          const long tok = slot >> 2;
#pragma unroll
          for (int ni = 0; ni < 4; ++ni) {
            const int col = n0 + wn * 64 + ni * 16 + fr;
            atomicAdd(&C[tok * (long)ldc + col], wgt * acc[mi][ni][rr]);
          }
        }
      } else {
        const long crow = crows ? (long)crows[r] : (cexp * e + r);
#pragma unroll
        for (int ni = 0; ni < 4; ++ni) {
          const int col = n0 + wn * 64 + ni * 16 + fr;
          C[crow * (long)ldc + col] = acc[mi][ni][rr];
        }
      }
    }
}

extern "C" void kernel_launch(void* const* d_in, const int* in_sizes, int n_in,
                              void* d_out, int out_size, void* d_ws, size_t ws_size,
                              hipStream_t stream)
{
  const float* x   = (const float*)d_in[0];
  const float* wg  = (const float*)d_in[1];
  const float* w1  = (const float*)d_in[2];
  const float* w3  = (const float*)d_in[3];
  const float* w2  = (const float*)d_in[4];
  const float* ws1 = (const float*)d_in[5];
  const float* ws3 = (const float*)d_in[6];
  const float* ws2 = (const float*)d_in[7];
  float* out = (float*)d_out;

  char* w = (char*)d_ws;
  int*   topi   = (int*)w;   w += (size_t)T_TOKENS * TOPK * 4;
  float* topw   = (float*)w; w += (size_t)T_TOKENS * TOPK * 4;
  int*   rowtok = (int*)w;   w += (size_t)NEXP * CAP * 4;
  int*   count  = (int*)w;   w += 256;
  uintptr_t a = (uintptr_t)w; a = (a + 255) & ~(uintptr_t)255; w = (char*)a;

  const size_t XSZ  = (size_t)T_TOKENS * HIDDEN;            // 4.19M
  const size_t WSI  = (size_t)2 * HIDDEN * SINTER;          // 11.5M  (interleaved ws1/ws3)
  const size_t WRI  = (size_t)2 * NEXP * HIDDEN * INTER;    // 92.3M  (interleaved w1/w3)
  const size_t HSSZ = (size_t)T_TOKENS * SINTER;            // 5.77M
  const size_t HRSZ = (size_t)NEXP * CAP * INTER;           // 17.3M

  unsigned short* xb  = (unsigned short*)w; w += XSZ * 2;   // 8.4 MB
  unsigned short* wSi = (unsigned short*)w; w += WSI * 2;   // 23.1 MB; reused as ws2T
  unsigned short* wRi = (unsigned short*)w; w += WRI * 2;   // 184.5 MB; reused as w2T
  unsigned short* hs  = (unsigned short*)w; w += HSSZ * 2;  // 11.5 MB
  unsigned short* hr  = (unsigned short*)w; w += HRSZ * 2;  // 34.6 MB
  unsigned short* wS2 = wSi;                                // after shared upgate GEMM
  unsigned short* wR2 = wRi;                                // after routed upgate GEMM

  router_kernel<<<T_TOKENS, 64, 0, stream>>>(x, wg, topi, topw);
  partition_kernel<<<1, 1024, 0, stream>>>(topi, topw, rowtok, count);
  cvt_x_kernel<<<(int)(XSZ / (256 * 8)), 256, 0, stream>>>(x, xb);

  // ---- L1: tcvt shared ws1/ws3 (standalone; first in chain) ----
  tcvt_w_kernel<<<dim3(HIDDEN / 64, SINTER / 64, 2), 256, 0, stream>>>(
      ws1, ws3, wSi, HIDDEN, SINTER, 0L, 2, 1, 0, 1);

  // ---- L2: shared upgate GEMM (704 blocks) ∥ tcvt routed w1/w3 (22528 blocks) ----
  {
    const int G = (T_TOKENS / 128) * (2 * SINTER / 128);          // 704
    const int TCVT = (HIDDEN / 64) * (INTER / 64) * (2 * NEXP);   // 22528
    gemm_bf<4, 2><<<G + TCVT, 256, 0, stream>>>(
        xb, HIDDEN, wSi, 0L, nullptr, hs, SINTER, nullptr,
        nullptr, 0, 0L, nullptr, 0L,
        nullptr, T_TOKENS, HIDDEN, T_TOKENS / 128, 2 * SINTER / 128,
        w1, w3, wRi, HIDDEN, INTER, (long)2 * HIDDEN * INTER, 2, NEXP, 0, 1,
        HIDDEN / 64, INTER / 64, G);
  }

  // ---- L3: routed upgate GEMM (2112) ∥ tcvt shared ws2 (1408) ----
  {
    const int G = (CAP / 128) * (2 * INTER / 128) * NEXP;         // 2112
    const int TCVT = (SINTER / 64) * (HIDDEN / 64);               // 1408
    gemm_bf<4, 2><<<G + TCVT, 256, 0, stream>>>(
        xb, HIDDEN, wRi, (long)2 * HIDDEN * INTER, nullptr, hr, INTER, nullptr,
        rowtok, 2, 0L, nullptr, (long)CAP,
        count, 0, HIDDEN, CAP / 128, 2 * INTER / 128,
        ws2, ws2, wS2, SINTER, HIDDEN, 0L, 1, 1, 0, 0,
        SINTER / 64, HIDDEN / 64, G);
  }

  // ---- L4: shared down GEMM (256) ∥ tcvt routed w2 (11264) ----
  {
    const int G = (T_TOKENS / 128) * (HIDDEN / 128);              // 256
    const int TCVT = (INTER / 64) * (HIDDEN / 64) * NEXP;         // 11264
    gemm_bf<4, 0><<<G + TCVT, 256, 0, stream>>>(
        hs, SINTER, wS2, 0L, out, nullptr, HIDDEN, nullptr,
        nullptr, 0, 0L, nullptr, 0L,
        nullptr, T_TOKENS, SINTER, T_TOKENS / 128, HIDDEN / 128,
        w2, w2, wR2, INTER, HIDDEN, (long)INTER * HIDDEN, 1, NEXP, 0, 0,
        INTER / 64, HIDDEN / 64, G);
  }

  // ---- L5: routed down GEMM, fused combine (1536 blocks, no tail) ----
  {
    const int G = (CAP / 128) * (HIDDEN / 128) * NEXP;            // 1536
    gemm_bf<4, 3><<<G, 256, 0, stream>>>(
        hr, INTER, wR2, (long)INTER * HIDDEN, out, nullptr, HIDDEN, topw,
        nullptr, 0, (long)CAP, rowtok, 0L,
        count, 0, INTER, CAP / 128, HIDDEN / 128,
        nullptr, nullptr, nullptr, 1, 1, 0L, 1, 1, 0, 0,
        1, 1, G);
  }
}